// Round 1
// 388.334 us; speedup vs baseline: 1.1092x; 1.1092x over previous
//
#include <hip/hip_runtime.h>
#include <cstdint>
#include <cstddef>

// Problem constants (match reference)
#define BTOT    4096
#define SRCLEN  128
#define INDIM   16
#define HDIM    64
#define SEQLEN  100
#define MEANS_N (BTOT * SEQLEN * 4)   // 1638400

// ---------- helpers ----------
// v_rcp_f32-based (no fast-math => plain 1.0f/x emits the exact-div sequence)
__device__ __forceinline__ float sigmoidf_(float x) {
    return __builtin_amdgcn_rcpf(1.0f + __expf(-x));
}
__device__ __forceinline__ float tanhf_(float x) {
    float e = __expf(2.0f * x);
    return 1.0f - 2.0f * __builtin_amdgcn_rcpf(e + 1.0f);
}
// gelu via Abramowitz-Stegun 7.1.26 erf (|err| < 1.5e-7) — replaces libm erff
__device__ __forceinline__ float gelu_fast(float x) {
    float z = fabsf(x) * 0.70710678118654752440f;
    float t = __builtin_amdgcn_rcpf(1.0f + 0.3275911f * z);
    float p = t * (0.254829592f +
              t * (-0.284496736f +
              t * (1.421413741f +
              t * (-1.453152027f +
              t * 1.061405429f))));
    float er = 1.0f - p * __expf(-z * z);
    er = copysignf(er, x);
    return 0.5f * x * (1.0f + er);
}

// ---------- bf16 split helpers (bf16x3 emulated-fp32 MFMA) ----------
typedef __attribute__((ext_vector_type(8))) short s8v;   // 8 bf16 (4 VGPRs) — MFMA A/B frag
typedef __attribute__((ext_vector_type(4))) float f4v;   // 4 fp32 — MFMA C/D frag

__device__ __forceinline__ unsigned short f2bf(float x) {  // RTNE float -> bf16 bits
    unsigned u = __float_as_uint(x);
    unsigned r = (u + 0x7FFFu + ((u >> 16) & 1u)) >> 16;
    return (unsigned short)r;
}
__device__ __forceinline__ float bf2f(unsigned short b) {
    return __uint_as_float(((unsigned)b) << 16);
}
__device__ __forceinline__ void split2(float4 a, float4 b, s8v& hi, s8v& lo) {
    float v[8] = {a.x, a.y, a.z, a.w, b.x, b.y, b.z, b.w};
    #pragma unroll
    for (int j = 0; j < 8; ++j) {
        unsigned short h = f2bf(v[j]);
        hi[j] = (short)h;
        lo[j] = (short)f2bf(v[j] - bf2f(h));
    }
}
__device__ __forceinline__ void split8(const float* v, s8v& hi, s8v& lo) {
    #pragma unroll
    for (int j = 0; j < 8; ++j) {
        unsigned short h = f2bf(v[j]);
        hi[j] = (short)h;
        lo[j] = (short)f2bf(v[j] - bf2f(h));
    }
}
__device__ __forceinline__ void load_bfrag(const float* p, s8v& hi, s8v& lo) {
    float4 a = *(const float4*)p;
    float4 b = *(const float4*)(p + 4);
    split2(a, b, hi, lo);
}

// Merge for the 8-batch activation rebalance:
// lanes 0-31 keep own_lo (their acc item j); lanes 32-63 receive the
// partner lane's (lane-32) acc item j+2. __shfl_xor(·,32) lowers to
// v_permlane64_b32 (half rotate == xor 32).
__device__ __forceinline__ float half_merge(float own_lo, float send_hi, int lane) {
    float rec = __shfl_xor(send_hi, 32, 64);
    return (lane < 32) ? own_lo : rec;
}

#define MFMA16(a, b, c) __builtin_amdgcn_mfma_f32_16x16x32_bf16((a), (b), (c), 0, 0, 0)

// =====================================================================
// Encoder GRU via MFMA (bf16x3).
// R3 restructure: 8 batches/block -> 512 blocks -> 2 blocks/CU so two
// independent recurrence streams overlap per SIMD (was 1 wave/SIMD,
// ~1100 idle cyc/step). Activations rebalanced to all 64 lanes via
// shfl_xor(32) (2 items/lane instead of 4 in half the lanes). x is
// pre-split to bf16 hi/lo in LDS in two 64-step chunks (kills the
// per-step split VALU). MFMA tile M=16 is half empty (rows 8-15 = 0).
// =====================================================================
__global__ __launch_bounds__(256, 2) void enc_mfma_kernel(
    const float* __restrict__ x,
    const float* __restrict__ Wih, const float* __restrict__ bih,
    const float* __restrict__ Whh, const float* __restrict__ bhh,
    float* __restrict__ enc_h)
{
    const int tid  = threadIdx.x;
    const int lane = tid & 63;
    const int w    = tid >> 6;     // wave 0..3
    const int col  = lane & 15;
    const int q    = lane >> 4;
    const int u    = w * 16 + col;
    const int b0   = blockIdx.x * 8;
    // post-rebalance batch row for item j: rows {0,1},{4,5},{2,3},{6,7} for q=0..3
    const int rj0  = (q & 1) * 4 + ((q >> 1) << 1);

    __shared__ __align__(16) unsigned short hiL[2][16][72];
    __shared__ __align__(16) unsigned short loL[2][16][72];
    __shared__ __align__(16) unsigned short xhi_l[64][8][16];  // 64-step chunk of x, bf16-hi
    __shared__ __align__(16) unsigned short xlo_l[64][8][16];  // bf16-lo

    // zero BOTH h double-buffers (rows 8-15 stay zero forever -> zero A rows)
    for (int i = tid; i < 2 * 16 * 72; i += 256) {
        ((unsigned short*)hiL)[i] = 0;
        ((unsigned short*)loL)[i] = 0;
    }

    // stage one 64-step chunk of x, pre-split into bf16 hi/lo
    auto stage_x = [&](int c) {
        #pragma unroll
        for (int k = 0; k < 8; ++k) {
            int f   = tid + k * 256;          // float4 index in this chunk (0..2047)
            int b   = f >> 8;                 // batch 0..7 (256 float4 per batch)
            int rem = f & 255;
            int tl  = rem >> 2;               // local t 0..63
            int d4  = (rem & 3) << 2;         // dim 0,4,8,12
            const float* xp = x + ((size_t)(b0 + b) * SRCLEN + (c * 64 + tl)) * INDIM + d4;
            float4 v = *(const float4*)xp;
            float vv[4] = {v.x, v.y, v.z, v.w};
            unsigned short hh[4], ll[4];
            #pragma unroll
            for (int j = 0; j < 4; ++j) {
                hh[j] = f2bf(vv[j]);
                ll[j] = f2bf(vv[j] - bf2f(hh[j]));
            }
            *(ushort4*)&xhi_l[tl][b][d4] = make_ushort4(hh[0], hh[1], hh[2], hh[3]);
            *(ushort4*)&xlo_l[tl][b][d4] = make_ushort4(ll[0], ll[1], ll[2], ll[3]);
        }
    };

    const s8v z8 = {0, 0, 0, 0, 0, 0, 0, 0};
    const f4v z4 = {0.0f, 0.0f, 0.0f, 0.0f};

    s8v brh[3], brl[3], bzh[3], bzl[3], bnhh[2], bnhl[2], bnxh, bnxl;
    load_bfrag(Whh + (size_t)u * 64 + q * 8,              brh[0], brl[0]);
    load_bfrag(Whh + (size_t)u * 64 + 32 + q * 8,         brh[1], brl[1]);
    load_bfrag(Whh + (size_t)(64 + u) * 64 + q * 8,       bzh[0], bzl[0]);
    load_bfrag(Whh + (size_t)(64 + u) * 64 + 32 + q * 8,  bzh[1], bzl[1]);
    load_bfrag(Whh + (size_t)(128 + u) * 64 + q * 8,      bnhh[0], bnhl[0]);
    load_bfrag(Whh + (size_t)(128 + u) * 64 + 32 + q * 8, bnhh[1], bnhl[1]);
    if (q < 2) {
        load_bfrag(Wih + (size_t)u * 16 + q * 8,         brh[2], brl[2]);
        load_bfrag(Wih + (size_t)(64 + u) * 16 + q * 8,  bzh[2], bzl[2]);
        load_bfrag(Wih + (size_t)(128 + u) * 16 + q * 8, bnxh, bnxl);
    } else {
        brh[2] = z8; brl[2] = z8; bzh[2] = z8; bzl[2] = z8; bnxh = z8; bnxl = z8;
    }

    const float br   = bih[u] + bhh[u];
    const float bz   = bih[u + 64] + bhh[u + 64];
    const float bnx  = bih[u + 128];
    const float bnh  = bhh[u + 128];

    stage_x(0);
    float hold2[2] = {0.0f, 0.0f};
    __syncthreads();

    int cur = 0;
    for (int t = 0; t < SRCLEN; ++t) {
        if (t == 64) {            // all waves done reading chunk 0 (barrier at t=63)
            stage_x(1);
            __syncthreads();
        }
        const int tl = t & 63;

        s8v xh, xl;
        if (q < 2 && col < 8) {
            xh = *(const s8v*)&xhi_l[tl][col][q * 8];
            xl = *(const s8v*)&xlo_l[tl][col][q * 8];
        } else { xh = z8; xl = z8; }

        const s8v ah0 = *(const s8v*)&hiL[cur][col][q * 8];
        const s8v al0 = *(const s8v*)&loL[cur][col][q * 8];
        const s8v ah1 = *(const s8v*)&hiL[cur][col][32 + q * 8];
        const s8v al1 = *(const s8v*)&loL[cur][col][32 + q * 8];

        f4v accr, accz, accnh, accnx;
        accr  = MFMA16(ah0, brh[0], z4);
        accz  = MFMA16(ah0, bzh[0], z4);
        accnh = MFMA16(ah0, bnhh[0], z4);
        accr  = MFMA16(ah0, brl[0], accr);
        accz  = MFMA16(ah0, bzl[0], accz);
        accnh = MFMA16(ah0, bnhl[0], accnh);
        accr  = MFMA16(al0, brh[0], accr);
        accz  = MFMA16(al0, bzh[0], accz);
        accnh = MFMA16(al0, bnhh[0], accnh);
        accr  = MFMA16(ah1, brh[1], accr);
        accz  = MFMA16(ah1, bzh[1], accz);
        accnh = MFMA16(ah1, bnhh[1], accnh);
        accr  = MFMA16(ah1, brl[1], accr);
        accz  = MFMA16(ah1, bzl[1], accz);
        accnh = MFMA16(ah1, bnhl[1], accnh);
        accr  = MFMA16(al1, brh[1], accr);
        accz  = MFMA16(al1, bzh[1], accz);
        accnh = MFMA16(al1, bnhh[1], accnh);
        accr  = MFMA16(xh, brh[2], accr);
        accz  = MFMA16(xh, bzh[2], accz);
        accnx = MFMA16(xh, bnxh, z4);
        accr  = MFMA16(xh, brl[2], accr);
        accz  = MFMA16(xh, bzl[2], accz);
        accnx = MFMA16(xh, bnxl, accnx);
        accr  = MFMA16(xl, brh[2], accr);
        accz  = MFMA16(xl, bzh[2], accz);
        accnx = MFMA16(xl, bnxh, accnx);

        // rebalance: 2 items/lane across all 64 lanes
        float pr[2], pz[2], pnh[2], pnx[2];
        pr[0]  = half_merge(accr[0],  accr[2],  lane);
        pr[1]  = half_merge(accr[1],  accr[3],  lane);
        pz[0]  = half_merge(accz[0],  accz[2],  lane);
        pz[1]  = half_merge(accz[1],  accz[3],  lane);
        pnh[0] = half_merge(accnh[0], accnh[2], lane);
        pnh[1] = half_merge(accnh[1], accnh[3], lane);
        pnx[0] = half_merge(accnx[0], accnx[2], lane);
        pnx[1] = half_merge(accnx[1], accnx[3], lane);

        const int nxt = cur ^ 1;
        #pragma unroll
        for (int j = 0; j < 2; ++j) {
            float r  = sigmoidf_(pr[j] + br);
            float zz = sigmoidf_(pz[j] + bz);
            float n  = tanhf_(pnx[j] + bnx + r * (pnh[j] + bnh));
            float h  = (1.0f - zz) * n + zz * hold2[j];
            hold2[j] = h;
            unsigned short hh = f2bf(h);
            hiL[nxt][rj0 + j][u] = hh;
            loL[nxt][rj0 + j][u] = f2bf(h - bf2f(hh));
        }
        __syncthreads();
        cur ^= 1;
    }

    enc_h[(size_t)(b0 + rj0) * HDIM + u]     = hold2[0];
    enc_h[(size_t)(b0 + rj0 + 1) * HDIM + u] = hold2[1];
}

// =====================================================================
// Decoder GRU via MFMA with out-projection folded into the recurrence.
// Same R3 restructure: 8 batches/block (512 blocks, 2 blocks/CU),
// shfl_xor(32) activation rebalance, rcp-based sigmoid/tanh.
// =====================================================================
__global__ __launch_bounds__(256, 2) void dec_mfma_kernel(
    const float* __restrict__ trg,
    const float* __restrict__ Wih, const float* __restrict__ bih,
    const float* __restrict__ Whh, const float* __restrict__ bhh,
    const float* __restrict__ outW, const float* __restrict__ outb,
    const float* __restrict__ embW, const float* __restrict__ embb,
    const float* __restrict__ enc_h,
    float* __restrict__ dec_o)
{
    const int tid  = threadIdx.x;
    const int lane = tid & 63;
    const int w    = tid >> 6;
    const int col  = lane & 15;
    const int q    = lane >> 4;
    const int u    = w * 16 + col;
    const int b0   = blockIdx.x * 8;
    const int rj0  = (q & 1) * 4 + ((q >> 1) << 1);

    __shared__ __align__(16) unsigned short hiL[2][16][72];
    __shared__ __align__(16) unsigned short loL[2][16][72];
    __shared__ float outW_l[16][64];   // staged outW (for Wcomb + o-frags)
    __shared__ float init_l[8][16];    // init_in per batch

    // ---- stage LDS: outW, init_in, zero pad rows, h0-split into buf0 ----
    for (int i = tid; i < 16 * 64; i += 256) outW_l[i >> 6][i & 63] = outW[i];
    if (tid < 128) {
        int b = tid >> 4, jj = tid & 15;
        float s = embb[jj];
        #pragma unroll
        for (int s4 = 0; s4 < 4; ++s4)
            s = fmaf(embW[jj * 4 + s4], trg[(size_t)(b0 + b) * 4 + s4], s);
        init_l[b][jj] = s;
    }
    // zero rows 8..15 of both buffers (never written with 8 batches)
    for (int i = tid; i < 2 * 8 * 72; i += 256) {
        int buf = i / (8 * 72);
        int rr  = (i / 72) & 7;
        int cc  = i % 72;
        hiL[buf][8 + rr][cc] = 0;
        loL[buf][8 + rr][cc] = 0;
    }
    if (tid < 128) {
        int idx = tid * 4;                  // 512 floats of h0 for this WG
        int bb = idx >> 6, uu = idx & 63;
        float4 v = *(const float4*)(enc_h + (size_t)(b0 + bb) * HDIM + uu);
        float vv[4] = {v.x, v.y, v.z, v.w};
        #pragma unroll
        for (int j = 0; j < 4; ++j) {
            unsigned short hh = f2bf(vv[j]);
            hiL[0][bb][uu + j] = hh;
            loL[0][bb][uu + j] = f2bf(vv[j] - bf2f(hh));
        }
    }
    // h_old for this lane's 2 (batch, unit=u) slots
    float hold2[2];
    hold2[0] = enc_h[(size_t)(b0 + rj0) * HDIM + u];
    hold2[1] = enc_h[(size_t)(b0 + rj0 + 1) * HDIM + u];

    __syncthreads();

    const f4v z4 = {0.0f, 0.0f, 0.0f, 0.0f};

    // ---- fp32 weight rows for this lane's k-slice (k = c*32 + q*8 + jj) ----
    float wh_r[16], wh_z[16], wh_n[16];
    #pragma unroll
    for (int c = 0; c < 2; ++c)
        #pragma unroll
        for (int jj = 0; jj < 8; ++jj) {
            int k = c * 32 + q * 8 + jj;
            wh_r[c * 8 + jj] = Whh[(size_t)u * 64 + k];
            wh_z[c * 8 + jj] = Whh[(size_t)(64 + u) * 64 + k];
            wh_n[c * 8 + jj] = Whh[(size_t)(128 + u) * 64 + k];
        }
    float wi_r[16], wi_z[16], wi_n[16];
    #pragma unroll
    for (int j = 0; j < 16; ++j) {
        wi_r[j] = Wih[(size_t)u * 16 + j];
        wi_z[j] = Wih[(size_t)(64 + u) * 16 + j];
        wi_n[j] = Wih[(size_t)(128 + u) * 16 + j];
    }

    // ---- Wcomb = Wih @ outW; merge into r/z; i_n separate ----
    float m_r[16], m_z[16], c_in[16];
    #pragma unroll
    for (int c = 0; c < 2; ++c)
        #pragma unroll
        for (int jj = 0; jj < 8; ++jj) {
            int k = c * 32 + q * 8 + jj;
            float sr = 0.0f, sz = 0.0f, sn = 0.0f;
            #pragma unroll
            for (int j = 0; j < 16; ++j) {
                float ow = outW_l[j][k];
                sr = fmaf(wi_r[j], ow, sr);
                sz = fmaf(wi_z[j], ow, sz);
                sn = fmaf(wi_n[j], ow, sn);
            }
            m_r[c * 8 + jj]  = wh_r[c * 8 + jj] + sr;
            m_z[c * 8 + jj]  = wh_z[c * 8 + jj] + sz;
            c_in[c * 8 + jj] = sn;
        }

    // ---- B-frags (steady state) ----
    s8v mrh[2], mrl[2], mzh[2], mzl[2], cinh[2], cinl[2], hnh[2], hnl[2];
    split8(m_r,      mrh[0],  mrl[0]);  split8(m_r + 8,  mrh[1],  mrl[1]);
    split8(m_z,      mzh[0],  mzl[0]);  split8(m_z + 8,  mzh[1],  mzl[1]);
    split8(c_in,     cinh[0], cinl[0]); split8(c_in + 8, cinh[1], cinl[1]);
    split8(wh_n,     hnh[0],  hnl[0]);  split8(wh_n + 8, hnh[1],  hnl[1]);
    // step-0 Whh-only r/z frags
    s8v r0h[2], r0l[2], z0h[2], z0l[2];
    split8(wh_r, r0h[0], r0l[0]); split8(wh_r + 8, r0h[1], r0l[1]);
    split8(wh_z, z0h[0], z0l[0]); split8(wh_z + 8, z0h[1], z0l[1]);
    // o-projection frags: B[n=col][k] = outW[col][k]
    s8v owh[2], owl[2];
    {
        float ov[16];
        #pragma unroll
        for (int c = 0; c < 2; ++c)
            #pragma unroll
            for (int jj = 0; jj < 8; ++jj)
                ov[c * 8 + jj] = outW_l[col][c * 32 + q * 8 + jj];
        split8(ov, owh[0], owl[0]); split8(ov + 8, owh[1], owl[1]);
    }

    // ---- folded biases ----
    float b_r = bhh[u] + bih[u];
    float b_z = bhh[u + 64] + bih[u + 64];
    float b_in = bih[u + 128];
    const float b_hn = bhh[u + 128];
    #pragma unroll
    for (int j = 0; j < 16; ++j) {
        float obj = outb[j];
        b_r  = fmaf(obj, wi_r[j], b_r);
        b_z  = fmaf(obj, wi_z[j], b_z);
        b_in = fmaf(obj, wi_n[j], b_in);
    }
    const float ob = outb[col];

    // ---- gi0 from init_in (per lane, its 2 post-rebalance rows) ----
    float g_r[2], g_z[2], g_n[2];
    #pragma unroll
    for (int j2 = 0; j2 < 2; ++j2) {
        int row = rj0 + j2;
        float sr = bih[u] + bhh[u];
        float sz = bih[u + 64] + bhh[u + 64];
        float sn = bih[u + 128];
        #pragma unroll
        for (int j = 0; j < 16; ++j) {
            float iv = init_l[row][j];
            sr = fmaf(wi_r[j], iv, sr);
            sz = fmaf(wi_z[j], iv, sz);
            sn = fmaf(wi_n[j], iv, sn);
        }
        g_r[j2] = sr; g_z[j2] = sz; g_n[j2] = sn;
    }

    // ---- step 0: h1 = GRU(h0, init_in) ----
    {
        const s8v ah0 = *(const s8v*)&hiL[0][col][q * 8];
        const s8v al0 = *(const s8v*)&loL[0][col][q * 8];
        const s8v ah1 = *(const s8v*)&hiL[0][col][32 + q * 8];
        const s8v al1 = *(const s8v*)&loL[0][col][32 + q * 8];
        f4v ar, az, ahn;
        ar  = MFMA16(ah0, r0h[0], z4);
        az  = MFMA16(ah0, z0h[0], z4);
        ahn = MFMA16(ah0, hnh[0], z4);
        ar  = MFMA16(ah0, r0l[0], ar);
        az  = MFMA16(ah0, z0l[0], az);
        ahn = MFMA16(ah0, hnl[0], ahn);
        ar  = MFMA16(al0, r0h[0], ar);
        az  = MFMA16(al0, z0h[0], az);
        ahn = MFMA16(al0, hnh[0], ahn);
        ar  = MFMA16(ah1, r0h[1], ar);
        az  = MFMA16(ah1, z0h[1], az);
        ahn = MFMA16(ah1, hnh[1], ahn);
        ar  = MFMA16(ah1, r0l[1], ar);
        az  = MFMA16(ah1, z0l[1], az);
        ahn = MFMA16(ah1, hnl[1], ahn);
        ar  = MFMA16(al1, r0h[1], ar);
        az  = MFMA16(al1, z0h[1], az);
        ahn = MFMA16(al1, hnh[1], ahn);

        float pr[2], pz[2], pnh[2];
        pr[0]  = half_merge(ar[0],  ar[2],  lane);
        pr[1]  = half_merge(ar[1],  ar[3],  lane);
        pz[0]  = half_merge(az[0],  az[2],  lane);
        pz[1]  = half_merge(az[1],  az[3],  lane);
        pnh[0] = half_merge(ahn[0], ahn[2], lane);
        pnh[1] = half_merge(ahn[1], ahn[3], lane);

        #pragma unroll
        for (int j = 0; j < 2; ++j) {
            float r  = sigmoidf_(pr[j] + g_r[j]);
            float zz = sigmoidf_(pz[j] + g_z[j]);
            float n  = tanhf_(g_n[j] + r * (pnh[j] + b_hn));
            float h  = (1.0f - zz) * n + zz * hold2[j];
            hold2[j] = h;
            unsigned short hh = f2bf(h);
            hiL[1][rj0 + j][u] = hh;
            loL[1][rj0 + j][u] = f2bf(h - bf2f(hh));
        }
        __syncthreads();
    }

    // ---- steps 1..99 (merged weights); o_{t-1} by wave 0 ----
    for (int t = 1; t < SEQLEN; ++t) {
        const int cur = t & 1;
        const s8v ah0 = *(const s8v*)&hiL[cur][col][q * 8];
        const s8v al0 = *(const s8v*)&loL[cur][col][q * 8];
        const s8v ah1 = *(const s8v*)&hiL[cur][col][32 + q * 8];
        const s8v al1 = *(const s8v*)&loL[cur][col][32 + q * 8];

        if (w == 0) {  // o_{t-1} = h_t @ outW^T + outb (rows 0-7 live in q<2)
            f4v oa;
            oa = MFMA16(ah0, owh[0], z4);
            oa = MFMA16(ah0, owl[0], oa);
            oa = MFMA16(al0, owh[0], oa);
            oa = MFMA16(ah1, owh[1], oa);
            oa = MFMA16(ah1, owl[1], oa);
            oa = MFMA16(al1, owh[1], oa);
            if (q < 2) {
                #pragma unroll
                for (int i = 0; i < 4; ++i)
                    dec_o[(((size_t)(b0 + q * 4 + i) * SEQLEN) + (t - 1)) * INDIM + col] = oa[i] + ob;
            }
        }

        f4v ar, az, ain, ahn;
        ar  = MFMA16(ah0, mrh[0], z4);
        az  = MFMA16(ah0, mzh[0], z4);
        ain = MFMA16(ah0, cinh[0], z4);
        ahn = MFMA16(ah0, hnh[0], z4);
        ar  = MFMA16(ah0, mrl[0], ar);
        az  = MFMA16(ah0, mzl[0], az);
        ain = MFMA16(ah0, cinl[0], ain);
        ahn = MFMA16(ah0, hnl[0], ahn);
        ar  = MFMA16(al0, mrh[0], ar);
        az  = MFMA16(al0, mzh[0], az);
        ain = MFMA16(al0, cinh[0], ain);
        ahn = MFMA16(al0, hnh[0], ahn);
        ar  = MFMA16(ah1, mrh[1], ar);
        az  = MFMA16(ah1, mzh[1], az);
        ain = MFMA16(ah1, cinh[1], ain);
        ahn = MFMA16(ah1, hnh[1], ahn);
        ar  = MFMA16(ah1, mrl[1], ar);
        az  = MFMA16(ah1, mzl[1], az);
        ain = MFMA16(ah1, cinl[1], ain);
        ahn = MFMA16(ah1, hnl[1], ahn);
        ar  = MFMA16(al1, mrh[1], ar);
        az  = MFMA16(al1, mzh[1], az);
        ain = MFMA16(al1, cinh[1], ain);
        ahn = MFMA16(al1, hnh[1], ahn);

        float pr[2], pz[2], pin[2], pnh[2];
        pr[0]  = half_merge(ar[0],  ar[2],  lane);
        pr[1]  = half_merge(ar[1],  ar[3],  lane);
        pz[0]  = half_merge(az[0],  az[2],  lane);
        pz[1]  = half_merge(az[1],  az[3],  lane);
        pin[0] = half_merge(ain[0], ain[2], lane);
        pin[1] = half_merge(ain[1], ain[3], lane);
        pnh[0] = half_merge(ahn[0], ahn[2], lane);
        pnh[1] = half_merge(ahn[1], ahn[3], lane);

        const int nxt = cur ^ 1;
        #pragma unroll
        for (int j = 0; j < 2; ++j) {
            float r  = sigmoidf_(pr[j] + b_r);
            float zz = sigmoidf_(pz[j] + b_z);
            float n  = tanhf_(pin[j] + b_in + r * (pnh[j] + b_hn));
            float h  = (1.0f - zz) * n + zz * hold2[j];
            hold2[j] = h;
            unsigned short hh = f2bf(h);
            hiL[nxt][rj0 + j][u] = hh;
            loL[nxt][rj0 + j][u] = f2bf(h - bf2f(hh));
        }
        __syncthreads();
    }

    // ---- epilogue: o_99 = h_100 @ outW^T + outb (buf 0) ----
    if (w == 0) {
        const s8v ah0 = *(const s8v*)&hiL[0][col][q * 8];
        const s8v al0 = *(const s8v*)&loL[0][col][q * 8];
        const s8v ah1 = *(const s8v*)&hiL[0][col][32 + q * 8];
        const s8v al1 = *(const s8v*)&loL[0][col][32 + q * 8];
        f4v oa;
        oa = MFMA16(ah0, owh[0], z4);
        oa = MFMA16(ah0, owl[0], oa);
        oa = MFMA16(al0, owh[0], oa);
        oa = MFMA16(ah1, owh[1], oa);
        oa = MFMA16(ah1, owl[1], oa);
        oa = MFMA16(al1, owh[1], oa);
        if (q < 2) {
            #pragma unroll
            for (int i = 0; i < 4; ++i)
                dec_o[(((size_t)(b0 + q * 4 + i) * SEQLEN) + (SEQLEN - 1)) * INDIM + col] = oa[i] + ob;
        }
    }
}

// =====================================================================
// Heads: 409600 independent rows; one thread per row.
// R3: gelu via fast erf poly (was libm erff) — pure VALU trim.
// =====================================================================
__global__ void heads_kernel(
    const float* __restrict__ dec_o,
    const float* __restrict__ mW1, const float* __restrict__ mb1,
    const float* __restrict__ mW2, const float* __restrict__ mb2,
    const float* __restrict__ cW1, const float* __restrict__ cb1,
    const float* __restrict__ cW2, const float* __restrict__ cb2,
    float* __restrict__ out)
{
    const size_t r = (size_t)blockIdx.x * 256 + threadIdx.x;  // 0..409599

    float o16[16];
    {
        const float4* op = (const float4*)(dec_o + r * 16);
        #pragma unroll
        for (int c = 0; c < 4; ++c) {
            float4 v = op[c];
            o16[4 * c + 0] = v.x; o16[4 * c + 1] = v.y;
            o16[4 * c + 2] = v.z; o16[4 * c + 3] = v.w;
        }
    }

    float m[4], cv[10];
    #pragma unroll
    for (int j = 0; j < 4; ++j)  m[j]  = mb2[j];
    #pragma unroll
    for (int j = 0; j < 10; ++j) cv[j] = cb2[j];

    #pragma unroll 8
    for (int hu = 0; hu < 64; ++hu) {
        const float* w1m = mW1 + hu * 16;
        float hm = mb1[hu];
        #pragma unroll
        for (int i = 0; i < 16; ++i) hm = fmaf(w1m[i], o16[i], hm);
        float gm = gelu_fast(hm);
        #pragma unroll
        for (int j = 0; j < 4; ++j) m[j] = fmaf(mW2[j * 64 + hu], gm, m[j]);

        const float* w1c = cW1 + hu * 16;
        float hc = cb1[hu];
        #pragma unroll
        for (int i = 0; i < 16; ++i) hc = fmaf(w1c[i], o16[i], hc);
        float gc = gelu_fast(hc);
        #pragma unroll
        for (int j = 0; j < 10; ++j) cv[j] = fmaf(cW2[j * 64 + hu], gc, cv[j]);
    }

    m[2] = fminf(fmaxf(m[2], -1.0f), 1.0f);
    m[3] = fminf(fmaxf(m[3], -1.0f), 1.0f);

    float* means = out;
    float* covs  = out + MEANS_N;
    #pragma unroll
    for (int j = 0; j < 4; ++j)  means[r * 4 + j]  = m[j];
    #pragma unroll
    for (int j = 0; j < 10; ++j) covs[r * 10 + j]  = cv[j];
}

// =====================================================================
extern "C" void kernel_launch(void* const* d_in, const int* in_sizes, int n_in,
                              void* d_out, int out_size, void* d_ws, size_t ws_size,
                              hipStream_t stream)
{
    const float* x    = (const float*)d_in[0];
    const float* trg  = (const float*)d_in[1];
    const float* eWih = (const float*)d_in[2];
    const float* ebih = (const float*)d_in[3];
    const float* eWhh = (const float*)d_in[4];
    const float* ebhh = (const float*)d_in[5];
    const float* dWih = (const float*)d_in[6];
    const float* dbih = (const float*)d_in[7];
    const float* dWhh = (const float*)d_in[8];
    const float* dbhh = (const float*)d_in[9];
    const float* outW = (const float*)d_in[10];
    const float* outb = (const float*)d_in[11];
    const float* embW = (const float*)d_in[12];
    const float* embb = (const float*)d_in[13];
    const float* mW1  = (const float*)d_in[14];
    const float* mb1  = (const float*)d_in[15];
    const float* mW2  = (const float*)d_in[16];
    const float* mb2  = (const float*)d_in[17];
    const float* cW1  = (const float*)d_in[18];
    const float* cb1  = (const float*)d_in[19];
    const float* cW2  = (const float*)d_in[20];
    const float* cb2  = (const float*)d_in[21];

    float* ws    = (float*)d_ws;
    float* enc_h = ws;                          // 4096*64      = 262144 floats
    float* dec_o = ws + (size_t)BTOT * HDIM;    // 4096*100*16  = 6553600 floats
    float* outp  = (float*)d_out;

    enc_mfma_kernel<<<dim3(BTOT / 8), dim3(256), 0, stream>>>(x, eWih, ebih, eWhh, ebhh, enc_h);
    dec_mfma_kernel<<<dim3(BTOT / 8), dim3(256), 0, stream>>>(trg, dWih, dbih, dWhh, dbhh,
                                                              outW, outb, embW, embb, enc_h, dec_o);
    heads_kernel<<<dim3((BTOT * SEQLEN) / 256), dim3(256), 0, stream>>>(
        dec_o, mW1, mb1, mW2, mb2, cW1, cb1, cW2, cb2, outp);
}

// Round 2
// 347.936 us; speedup vs baseline: 1.2380x; 1.1161x over previous
//
#include <hip/hip_runtime.h>
#include <cstdint>
#include <cstddef>

// Problem constants (match reference)
#define BTOT    4096
#define SRCLEN  128
#define INDIM   16
#define HDIM    64
#define SEQLEN  100
#define MEANS_N (BTOT * SEQLEN * 4)   // 1638400

// ---------- helpers ----------
// v_rcp_f32-based (no fast-math => plain 1.0f/x emits the exact-div sequence)
__device__ __forceinline__ float sigmoidf_(float x) {
    return __builtin_amdgcn_rcpf(1.0f + __expf(-x));
}
__device__ __forceinline__ float tanhf_(float x) {
    float e = __expf(2.0f * x);
    return 1.0f - 2.0f * __builtin_amdgcn_rcpf(e + 1.0f);
}
// gelu via Abramowitz-Stegun 7.1.26 erf (|err| < 1.5e-7) — replaces libm erff
__device__ __forceinline__ float gelu_fast(float x) {
    float z = fabsf(x) * 0.70710678118654752440f;
    float t = __builtin_amdgcn_rcpf(1.0f + 0.3275911f * z);
    float p = t * (0.254829592f +
              t * (-0.284496736f +
              t * (1.421413741f +
              t * (-1.453152027f +
              t * 1.061405429f))));
    float er = 1.0f - p * __expf(-z * z);
    er = copysignf(er, x);
    return 0.5f * x * (1.0f + er);
}

// ---------- bf16 split helpers (bf16x3 emulated-fp32 MFMA) ----------
typedef __attribute__((ext_vector_type(8))) short s8v;   // 8 bf16 (4 VGPRs) — MFMA A/B frag
typedef __attribute__((ext_vector_type(4))) float f4v;   // 4 fp32 — MFMA C/D frag

__device__ __forceinline__ unsigned short f2bf(float x) {  // RTNE float -> bf16 bits
    unsigned u = __float_as_uint(x);
    unsigned r = (u + 0x7FFFu + ((u >> 16) & 1u)) >> 16;
    return (unsigned short)r;
}
__device__ __forceinline__ float bf2f(unsigned short b) {
    return __uint_as_float(((unsigned)b) << 16);
}
__device__ __forceinline__ void split2(float4 a, float4 b, s8v& hi, s8v& lo) {
    float v[8] = {a.x, a.y, a.z, a.w, b.x, b.y, b.z, b.w};
    #pragma unroll
    for (int j = 0; j < 8; ++j) {
        unsigned short h = f2bf(v[j]);
        hi[j] = (short)h;
        lo[j] = (short)f2bf(v[j] - bf2f(h));
    }
}
__device__ __forceinline__ void split8(const float* v, s8v& hi, s8v& lo) {
    #pragma unroll
    for (int j = 0; j < 8; ++j) {
        unsigned short h = f2bf(v[j]);
        hi[j] = (short)h;
        lo[j] = (short)f2bf(v[j] - bf2f(h));
    }
}
__device__ __forceinline__ void load_bfrag(const float* p, s8v& hi, s8v& lo) {
    float4 a = *(const float4*)p;
    float4 b = *(const float4*)(p + 4);
    split2(a, b, hi, lo);
}

// Merge for the 8-batch activation rebalance, via gfx950 v_permlane32_swap:
// result lanes 0-31 = own_lo (this lane), lanes 32-63 = send_hi from lane-32.
// One VALU op replaces ds_bpermute + v_cndmask (+ lgkmcnt wait).
typedef __attribute__((ext_vector_type(2))) unsigned int u2v;
__device__ __forceinline__ float half_merge(float own_lo, float send_hi) {
    u2v r = __builtin_amdgcn_permlane32_swap(__float_as_uint(own_lo),
                                             __float_as_uint(send_hi),
                                             false, false);
    return __uint_as_float(r[0]);
}

#define MFMA16(a, b, c) __builtin_amdgcn_mfma_f32_16x16x32_bf16((a), (b), (c), 0, 0, 0)

// =====================================================================
// Encoder GRU via MFMA (bf16x3). 8 batches/block, 512 blocks, 2 blocks/CU.
// R4: permlane32_swap merge (no ds_bpermute), x tile gains a zeroed
// batch-row 8 so ALL lanes read x-frags unconditionally (q>=2 lanes
// broadcast-read zeros) — removes the divergent z8 path per step.
// =====================================================================
__global__ __launch_bounds__(256, 2) void enc_mfma_kernel(
    const float* __restrict__ x,
    const float* __restrict__ Wih, const float* __restrict__ bih,
    const float* __restrict__ Whh, const float* __restrict__ bhh,
    float* __restrict__ enc_h)
{
    const int tid  = threadIdx.x;
    const int lane = tid & 63;
    const int w    = tid >> 6;     // wave 0..3
    const int col  = lane & 15;
    const int q    = lane >> 4;
    const int u    = w * 16 + col;
    const int b0   = blockIdx.x * 8;
    // post-rebalance batch row for item j: rows {0,1},{4,5},{2,3},{6,7} for q=0..3
    const int rj0  = (q & 1) * 4 + ((q >> 1) << 1);

    __shared__ __align__(16) unsigned short hiL[2][16][72];
    __shared__ __align__(16) unsigned short loL[2][16][72];
    // [tl][batch 0..7 | zero-row 8][dim] — row 8 is all-zero so lanes q>=2
    // can read a valid zero fragment with no divergence.
    __shared__ __align__(16) unsigned short xhi_l[64][9][16];
    __shared__ __align__(16) unsigned short xlo_l[64][9][16];

    // zero BOTH h double-buffers (rows 8-15 stay zero forever -> zero A rows)
    for (int i = tid; i < 2 * 16 * 72; i += 256) {
        ((unsigned short*)hiL)[i] = 0;
        ((unsigned short*)loL)[i] = 0;
    }
    // zero the x pad row 8 (once)
    for (int i = tid; i < 64 * 16; i += 256) {
        xhi_l[i >> 4][8][i & 15] = 0;
        xlo_l[i >> 4][8][i & 15] = 0;
    }

    // stage one 64-step chunk of x, pre-split into bf16 hi/lo
    auto stage_x = [&](int c) {
        #pragma unroll
        for (int k = 0; k < 8; ++k) {
            int f   = tid + k * 256;          // float4 index in this chunk (0..2047)
            int b   = f >> 8;                 // batch 0..7 (256 float4 per batch)
            int rem = f & 255;
            int tl  = rem >> 2;               // local t 0..63
            int d4  = (rem & 3) << 2;         // dim 0,4,8,12
            const float* xp = x + ((size_t)(b0 + b) * SRCLEN + (c * 64 + tl)) * INDIM + d4;
            float4 v = *(const float4*)xp;
            float vv[4] = {v.x, v.y, v.z, v.w};
            unsigned short hh[4], ll[4];
            #pragma unroll
            for (int j = 0; j < 4; ++j) {
                hh[j] = f2bf(vv[j]);
                ll[j] = f2bf(vv[j] - bf2f(hh[j]));
            }
            *(ushort4*)&xhi_l[tl][b][d4] = make_ushort4(hh[0], hh[1], hh[2], hh[3]);
            *(ushort4*)&xlo_l[tl][b][d4] = make_ushort4(ll[0], ll[1], ll[2], ll[3]);
        }
    };

    const s8v z8 = {0, 0, 0, 0, 0, 0, 0, 0};
    const f4v z4 = {0.0f, 0.0f, 0.0f, 0.0f};

    s8v brh[3], brl[3], bzh[3], bzl[3], bnhh[2], bnhl[2], bnxh, bnxl;
    load_bfrag(Whh + (size_t)u * 64 + q * 8,              brh[0], brl[0]);
    load_bfrag(Whh + (size_t)u * 64 + 32 + q * 8,         brh[1], brl[1]);
    load_bfrag(Whh + (size_t)(64 + u) * 64 + q * 8,       bzh[0], bzl[0]);
    load_bfrag(Whh + (size_t)(64 + u) * 64 + 32 + q * 8,  bzh[1], bzl[1]);
    load_bfrag(Whh + (size_t)(128 + u) * 64 + q * 8,      bnhh[0], bnhl[0]);
    load_bfrag(Whh + (size_t)(128 + u) * 64 + 32 + q * 8, bnhh[1], bnhl[1]);
    if (q < 2) {
        load_bfrag(Wih + (size_t)u * 16 + q * 8,         brh[2], brl[2]);
        load_bfrag(Wih + (size_t)(64 + u) * 16 + q * 8,  bzh[2], bzl[2]);
        load_bfrag(Wih + (size_t)(128 + u) * 16 + q * 8, bnxh, bnxl);
    } else {
        brh[2] = z8; brl[2] = z8; bzh[2] = z8; bzl[2] = z8; bnxh = z8; bnxl = z8;
    }

    const float br   = bih[u] + bhh[u];
    const float bz   = bih[u + 64] + bhh[u + 64];
    const float bnx  = bih[u + 128];
    const float bnh  = bhh[u + 128];

    // unconditional x-frag read bases: lanes q>=2 point at the zero row 8
    const int xb   = (q < 2) ? (col & 7) : 8;
    const int xoff = (q & 1) * 8;
    const unsigned short* xh_base = &xhi_l[0][xb][xoff];
    const unsigned short* xl_base = &xlo_l[0][xb][xoff];

    stage_x(0);
    float hold2[2] = {0.0f, 0.0f};
    __syncthreads();

    int cur = 0;
    for (int t = 0; t < SRCLEN; ++t) {
        if (t == 64) {            // all waves done reading chunk 0 (barrier at t=63)
            stage_x(1);
            __syncthreads();
        }
        const int tl = t & 63;

        const s8v xh = *(const s8v*)(xh_base + (size_t)tl * 144);
        const s8v xl = *(const s8v*)(xl_base + (size_t)tl * 144);

        const s8v ah0 = *(const s8v*)&hiL[cur][col][q * 8];
        const s8v al0 = *(const s8v*)&loL[cur][col][q * 8];
        const s8v ah1 = *(const s8v*)&hiL[cur][col][32 + q * 8];
        const s8v al1 = *(const s8v*)&loL[cur][col][32 + q * 8];

        f4v accr, accz, accnh, accnx;
        accr  = MFMA16(ah0, brh[0], z4);
        accz  = MFMA16(ah0, bzh[0], z4);
        accnh = MFMA16(ah0, bnhh[0], z4);
        accr  = MFMA16(ah0, brl[0], accr);
        accz  = MFMA16(ah0, bzl[0], accz);
        accnh = MFMA16(ah0, bnhl[0], accnh);
        accr  = MFMA16(al0, brh[0], accr);
        accz  = MFMA16(al0, bzh[0], accz);
        accnh = MFMA16(al0, bnhh[0], accnh);
        accr  = MFMA16(ah1, brh[1], accr);
        accz  = MFMA16(ah1, bzh[1], accz);
        accnh = MFMA16(ah1, bnhh[1], accnh);
        accr  = MFMA16(ah1, brl[1], accr);
        accz  = MFMA16(ah1, bzl[1], accz);
        accnh = MFMA16(ah1, bnhl[1], accnh);
        accr  = MFMA16(al1, brh[1], accr);
        accz  = MFMA16(al1, bzh[1], accz);
        accnh = MFMA16(al1, bnhh[1], accnh);
        accr  = MFMA16(xh, brh[2], accr);
        accz  = MFMA16(xh, bzh[2], accz);
        accnx = MFMA16(xh, bnxh, z4);
        accr  = MFMA16(xh, brl[2], accr);
        accz  = MFMA16(xh, bzl[2], accz);
        accnx = MFMA16(xh, bnxl, accnx);
        accr  = MFMA16(xl, brh[2], accr);
        accz  = MFMA16(xl, bzh[2], accz);
        accnx = MFMA16(xl, bnxh, accnx);

        // rebalance: 2 items/lane across all 64 lanes (v_permlane32_swap)
        float pr[2], pz[2], pnh[2], pnx[2];
        pr[0]  = half_merge(accr[0],  accr[2]);
        pr[1]  = half_merge(accr[1],  accr[3]);
        pz[0]  = half_merge(accz[0],  accz[2]);
        pz[1]  = half_merge(accz[1],  accz[3]);
        pnh[0] = half_merge(accnh[0], accnh[2]);
        pnh[1] = half_merge(accnh[1], accnh[3]);
        pnx[0] = half_merge(accnx[0], accnx[2]);
        pnx[1] = half_merge(accnx[1], accnx[3]);

        const int nxt = cur ^ 1;
        #pragma unroll
        for (int j = 0; j < 2; ++j) {
            float r  = sigmoidf_(pr[j] + br);
            float zz = sigmoidf_(pz[j] + bz);
            float n  = tanhf_(pnx[j] + bnx + r * (pnh[j] + bnh));
            float h  = (1.0f - zz) * n + zz * hold2[j];
            hold2[j] = h;
            unsigned short hh = f2bf(h);
            hiL[nxt][rj0 + j][u] = hh;
            loL[nxt][rj0 + j][u] = f2bf(h - bf2f(hh));
        }
        __syncthreads();
        cur ^= 1;
    }

    enc_h[(size_t)(b0 + rj0) * HDIM + u]     = hold2[0];
    enc_h[(size_t)(b0 + rj0 + 1) * HDIM + u] = hold2[1];
}

// =====================================================================
// Decoder GRU via MFMA with out-projection folded into the recurrence.
// R4: o-projection round-robins over waves (was always wave 0 — wave 0
// carried +6 MFMA/step on the barrier-synced critical path); permlane
// merge replaces shfl.
// =====================================================================
__global__ __launch_bounds__(256, 2) void dec_mfma_kernel(
    const float* __restrict__ trg,
    const float* __restrict__ Wih, const float* __restrict__ bih,
    const float* __restrict__ Whh, const float* __restrict__ bhh,
    const float* __restrict__ outW, const float* __restrict__ outb,
    const float* __restrict__ embW, const float* __restrict__ embb,
    const float* __restrict__ enc_h,
    float* __restrict__ dec_o)
{
    const int tid  = threadIdx.x;
    const int lane = tid & 63;
    const int w    = tid >> 6;
    const int col  = lane & 15;
    const int q    = lane >> 4;
    const int u    = w * 16 + col;
    const int b0   = blockIdx.x * 8;
    const int rj0  = (q & 1) * 4 + ((q >> 1) << 1);

    __shared__ __align__(16) unsigned short hiL[2][16][72];
    __shared__ __align__(16) unsigned short loL[2][16][72];
    __shared__ float outW_l[16][64];   // staged outW (for Wcomb + o-frags)
    __shared__ float init_l[8][16];    // init_in per batch

    // ---- stage LDS: outW, init_in, zero pad rows, h0-split into buf0 ----
    for (int i = tid; i < 16 * 64; i += 256) outW_l[i >> 6][i & 63] = outW[i];
    if (tid < 128) {
        int b = tid >> 4, jj = tid & 15;
        float s = embb[jj];
        #pragma unroll
        for (int s4 = 0; s4 < 4; ++s4)
            s = fmaf(embW[jj * 4 + s4], trg[(size_t)(b0 + b) * 4 + s4], s);
        init_l[b][jj] = s;
    }
    // zero rows 8..15 of both buffers (never written with 8 batches)
    for (int i = tid; i < 2 * 8 * 72; i += 256) {
        int buf = i / (8 * 72);
        int rr  = (i / 72) & 7;
        int cc  = i % 72;
        hiL[buf][8 + rr][cc] = 0;
        loL[buf][8 + rr][cc] = 0;
    }
    if (tid < 128) {
        int idx = tid * 4;                  // 512 floats of h0 for this WG
        int bb = idx >> 6, uu = idx & 63;
        float4 v = *(const float4*)(enc_h + (size_t)(b0 + bb) * HDIM + uu);
        float vv[4] = {v.x, v.y, v.z, v.w};
        #pragma unroll
        for (int j = 0; j < 4; ++j) {
            unsigned short hh = f2bf(vv[j]);
            hiL[0][bb][uu + j] = hh;
            loL[0][bb][uu + j] = f2bf(vv[j] - bf2f(hh));
        }
    }
    // h_old for this lane's 2 (batch, unit=u) slots
    float hold2[2];
    hold2[0] = enc_h[(size_t)(b0 + rj0) * HDIM + u];
    hold2[1] = enc_h[(size_t)(b0 + rj0 + 1) * HDIM + u];

    __syncthreads();

    const f4v z4 = {0.0f, 0.0f, 0.0f, 0.0f};

    // ---- fp32 weight rows for this lane's k-slice (k = c*32 + q*8 + jj) ----
    float wh_r[16], wh_z[16], wh_n[16];
    #pragma unroll
    for (int c = 0; c < 2; ++c)
        #pragma unroll
        for (int jj = 0; jj < 8; ++jj) {
            int k = c * 32 + q * 8 + jj;
            wh_r[c * 8 + jj] = Whh[(size_t)u * 64 + k];
            wh_z[c * 8 + jj] = Whh[(size_t)(64 + u) * 64 + k];
            wh_n[c * 8 + jj] = Whh[(size_t)(128 + u) * 64 + k];
        }
    float wi_r[16], wi_z[16], wi_n[16];
    #pragma unroll
    for (int j = 0; j < 16; ++j) {
        wi_r[j] = Wih[(size_t)u * 16 + j];
        wi_z[j] = Wih[(size_t)(64 + u) * 16 + j];
        wi_n[j] = Wih[(size_t)(128 + u) * 16 + j];
    }

    // ---- Wcomb = Wih @ outW; merge into r/z; i_n separate ----
    float m_r[16], m_z[16], c_in[16];
    #pragma unroll
    for (int c = 0; c < 2; ++c)
        #pragma unroll
        for (int jj = 0; jj < 8; ++jj) {
            int k = c * 32 + q * 8 + jj;
            float sr = 0.0f, sz = 0.0f, sn = 0.0f;
            #pragma unroll
            for (int j = 0; j < 16; ++j) {
                float ow = outW_l[j][k];
                sr = fmaf(wi_r[j], ow, sr);
                sz = fmaf(wi_z[j], ow, sz);
                sn = fmaf(wi_n[j], ow, sn);
            }
            m_r[c * 8 + jj]  = wh_r[c * 8 + jj] + sr;
            m_z[c * 8 + jj]  = wh_z[c * 8 + jj] + sz;
            c_in[c * 8 + jj] = sn;
        }

    // ---- B-frags (steady state) ----
    s8v mrh[2], mrl[2], mzh[2], mzl[2], cinh[2], cinl[2], hnh[2], hnl[2];
    split8(m_r,      mrh[0],  mrl[0]);  split8(m_r + 8,  mrh[1],  mrl[1]);
    split8(m_z,      mzh[0],  mzl[0]);  split8(m_z + 8,  mzh[1],  mzl[1]);
    split8(c_in,     cinh[0], cinl[0]); split8(c_in + 8, cinh[1], cinl[1]);
    split8(wh_n,     hnh[0],  hnl[0]);  split8(wh_n + 8, hnh[1],  hnl[1]);
    // step-0 Whh-only r/z frags
    s8v r0h[2], r0l[2], z0h[2], z0l[2];
    split8(wh_r, r0h[0], r0l[0]); split8(wh_r + 8, r0h[1], r0l[1]);
    split8(wh_z, z0h[0], z0l[0]); split8(wh_z + 8, z0h[1], z0l[1]);
    // o-projection frags: B[n=col][k] = outW[col][k]
    s8v owh[2], owl[2];
    {
        float ov[16];
        #pragma unroll
        for (int c = 0; c < 2; ++c)
            #pragma unroll
            for (int jj = 0; jj < 8; ++jj)
                ov[c * 8 + jj] = outW_l[col][c * 32 + q * 8 + jj];
        split8(ov, owh[0], owl[0]); split8(ov + 8, owh[1], owl[1]);
    }

    // ---- folded biases ----
    float b_r = bhh[u] + bih[u];
    float b_z = bhh[u + 64] + bih[u + 64];
    float b_in = bih[u + 128];
    const float b_hn = bhh[u + 128];
    #pragma unroll
    for (int j = 0; j < 16; ++j) {
        float obj = outb[j];
        b_r  = fmaf(obj, wi_r[j], b_r);
        b_z  = fmaf(obj, wi_z[j], b_z);
        b_in = fmaf(obj, wi_n[j], b_in);
    }
    const float ob = outb[col];

    // ---- gi0 from init_in (per lane, its 2 post-rebalance rows) ----
    float g_r[2], g_z[2], g_n[2];
    #pragma unroll
    for (int j2 = 0; j2 < 2; ++j2) {
        int row = rj0 + j2;
        float sr = bih[u] + bhh[u];
        float sz = bih[u + 64] + bhh[u + 64];
        float sn = bih[u + 128];
        #pragma unroll
        for (int j = 0; j < 16; ++j) {
            float iv = init_l[row][j];
            sr = fmaf(wi_r[j], iv, sr);
            sz = fmaf(wi_z[j], iv, sz);
            sn = fmaf(wi_n[j], iv, sn);
        }
        g_r[j2] = sr; g_z[j2] = sz; g_n[j2] = sn;
    }

    // ---- step 0: h1 = GRU(h0, init_in) ----
    {
        const s8v ah0 = *(const s8v*)&hiL[0][col][q * 8];
        const s8v al0 = *(const s8v*)&loL[0][col][q * 8];
        const s8v ah1 = *(const s8v*)&hiL[0][col][32 + q * 8];
        const s8v al1 = *(const s8v*)&loL[0][col][32 + q * 8];
        f4v ar, az, ahn;
        ar  = MFMA16(ah0, r0h[0], z4);
        az  = MFMA16(ah0, z0h[0], z4);
        ahn = MFMA16(ah0, hnh[0], z4);
        ar  = MFMA16(ah0, r0l[0], ar);
        az  = MFMA16(ah0, z0l[0], az);
        ahn = MFMA16(ah0, hnl[0], ahn);
        ar  = MFMA16(al0, r0h[0], ar);
        az  = MFMA16(al0, z0h[0], az);
        ahn = MFMA16(al0, hnh[0], ahn);
        ar  = MFMA16(ah1, r0h[1], ar);
        az  = MFMA16(ah1, z0h[1], az);
        ahn = MFMA16(ah1, hnh[1], ahn);
        ar  = MFMA16(ah1, r0l[1], ar);
        az  = MFMA16(ah1, z0l[1], az);
        ahn = MFMA16(ah1, hnl[1], ahn);
        ar  = MFMA16(al1, r0h[1], ar);
        az  = MFMA16(al1, z0h[1], az);
        ahn = MFMA16(al1, hnh[1], ahn);

        float pr[2], pz[2], pnh[2];
        pr[0]  = half_merge(ar[0],  ar[2]);
        pr[1]  = half_merge(ar[1],  ar[3]);
        pz[0]  = half_merge(az[0],  az[2]);
        pz[1]  = half_merge(az[1],  az[3]);
        pnh[0] = half_merge(ahn[0], ahn[2]);
        pnh[1] = half_merge(ahn[1], ahn[3]);

        #pragma unroll
        for (int j = 0; j < 2; ++j) {
            float r  = sigmoidf_(pr[j] + g_r[j]);
            float zz = sigmoidf_(pz[j] + g_z[j]);
            float n  = tanhf_(g_n[j] + r * (pnh[j] + b_hn));
            float h  = (1.0f - zz) * n + zz * hold2[j];
            hold2[j] = h;
            unsigned short hh = f2bf(h);
            hiL[1][rj0 + j][u] = hh;
            loL[1][rj0 + j][u] = f2bf(h - bf2f(hh));
        }
        __syncthreads();
    }

    // ---- steps 1..99 (merged weights); o_{t-1} by wave (t-1)&3 ----
    for (int t = 1; t < SEQLEN; ++t) {
        const int cur = t & 1;
        const s8v ah0 = *(const s8v*)&hiL[cur][col][q * 8];
        const s8v al0 = *(const s8v*)&loL[cur][col][q * 8];
        const s8v ah1 = *(const s8v*)&hiL[cur][col][32 + q * 8];
        const s8v al1 = *(const s8v*)&loL[cur][col][32 + q * 8];

        if (w == ((t - 1) & 3)) {  // o_{t-1} = h_t @ outW^T + outb (round-robin)
            f4v oa;
            oa = MFMA16(ah0, owh[0], z4);
            oa = MFMA16(ah0, owl[0], oa);
            oa = MFMA16(al0, owh[0], oa);
            oa = MFMA16(ah1, owh[1], oa);
            oa = MFMA16(ah1, owl[1], oa);
            oa = MFMA16(al1, owh[1], oa);
            if (q < 2) {
                #pragma unroll
                for (int i = 0; i < 4; ++i)
                    dec_o[(((size_t)(b0 + q * 4 + i) * SEQLEN) + (t - 1)) * INDIM + col] = oa[i] + ob;
            }
        }

        f4v ar, az, ain, ahn;
        ar  = MFMA16(ah0, mrh[0], z4);
        az  = MFMA16(ah0, mzh[0], z4);
        ain = MFMA16(ah0, cinh[0], z4);
        ahn = MFMA16(ah0, hnh[0], z4);
        ar  = MFMA16(ah0, mrl[0], ar);
        az  = MFMA16(ah0, mzl[0], az);
        ain = MFMA16(ah0, cinl[0], ain);
        ahn = MFMA16(ah0, hnl[0], ahn);
        ar  = MFMA16(al0, mrh[0], ar);
        az  = MFMA16(al0, mzh[0], az);
        ain = MFMA16(al0, cinh[0], ain);
        ahn = MFMA16(al0, hnh[0], ahn);
        ar  = MFMA16(ah1, mrh[1], ar);
        az  = MFMA16(ah1, mzh[1], az);
        ain = MFMA16(ah1, cinh[1], ain);
        ahn = MFMA16(ah1, hnh[1], ahn);
        ar  = MFMA16(ah1, mrl[1], ar);
        az  = MFMA16(ah1, mzl[1], az);
        ain = MFMA16(ah1, cinl[1], ain);
        ahn = MFMA16(ah1, hnl[1], ahn);
        ar  = MFMA16(al1, mrh[1], ar);
        az  = MFMA16(al1, mzh[1], az);
        ain = MFMA16(al1, cinh[1], ain);
        ahn = MFMA16(al1, hnh[1], ahn);

        float pr[2], pz[2], pin[2], pnh[2];
        pr[0]  = half_merge(ar[0],  ar[2]);
        pr[1]  = half_merge(ar[1],  ar[3]);
        pz[0]  = half_merge(az[0],  az[2]);
        pz[1]  = half_merge(az[1],  az[3]);
        pin[0] = half_merge(ain[0], ain[2]);
        pin[1] = half_merge(ain[1], ain[3]);
        pnh[0] = half_merge(ahn[0], ahn[2]);
        pnh[1] = half_merge(ahn[1], ahn[3]);

        const int nxt = cur ^ 1;
        #pragma unroll
        for (int j = 0; j < 2; ++j) {
            float r  = sigmoidf_(pr[j] + b_r);
            float zz = sigmoidf_(pz[j] + b_z);
            float n  = tanhf_(pin[j] + b_in + r * (pnh[j] + b_hn));
            float h  = (1.0f - zz) * n + zz * hold2[j];
            hold2[j] = h;
            unsigned short hh = f2bf(h);
            hiL[nxt][rj0 + j][u] = hh;
            loL[nxt][rj0 + j][u] = f2bf(h - bf2f(hh));
        }
        __syncthreads();
    }

    // ---- epilogue: o_99 = h_100 @ outW^T + outb (buf 0) ----
    if (w == 0) {
        const s8v ah0 = *(const s8v*)&hiL[0][col][q * 8];
        const s8v al0 = *(const s8v*)&loL[0][col][q * 8];
        const s8v ah1 = *(const s8v*)&hiL[0][col][32 + q * 8];
        const s8v al1 = *(const s8v*)&loL[0][col][32 + q * 8];
        f4v oa;
        oa = MFMA16(ah0, owh[0], z4);
        oa = MFMA16(ah0, owl[0], oa);
        oa = MFMA16(al0, owh[0], oa);
        oa = MFMA16(ah1, owh[1], oa);
        oa = MFMA16(ah1, owl[1], oa);
        oa = MFMA16(al1, owh[1], oa);
        if (q < 2) {
            #pragma unroll
            for (int i = 0; i < 4; ++i)
                dec_o[(((size_t)(b0 + q * 4 + i) * SEQLEN) + (SEQLEN - 1)) * INDIM + col] = oa[i] + ob;
        }
    }
}

// =====================================================================
// Heads: 409600 independent rows; one thread per row.
// R4: ALL weights staged to LDS once per block (was 46 redundant uniform
// global loads per hu-iteration = ~2944 per thread, issue-bound). LDS
// same-address reads broadcast conflict-free; 12 ds_read_b128/iter vs
// ~70 VALU/iter.
// =====================================================================
__global__ __launch_bounds__(256) void heads_kernel(
    const float* __restrict__ dec_o,
    const float* __restrict__ mW1, const float* __restrict__ mb1,
    const float* __restrict__ mW2, const float* __restrict__ mb2,
    const float* __restrict__ cW1, const float* __restrict__ cb1,
    const float* __restrict__ cW2, const float* __restrict__ cb2,
    float* __restrict__ out)
{
    const int tid = threadIdx.x;

    __shared__ __align__(16) float lW1m[64][16];
    __shared__ __align__(16) float lW1c[64][16];
    // [hu][0..3]=mW2 rows, [4..13]=cW2 rows, [14]=mb1, [15]=cb1
    __shared__ __align__(16) float lW2t[64][16];

    for (int i = tid; i < 1024; i += 256) {
        lW1m[i >> 4][i & 15] = mW1[i];
        lW1c[i >> 4][i & 15] = cW1[i];
    }
    if (tid < 64) {
        #pragma unroll
        for (int j = 0; j < 4; ++j)  lW2t[tid][j]     = mW2[j * 64 + tid];
        #pragma unroll
        for (int j = 0; j < 10; ++j) lW2t[tid][4 + j] = cW2[j * 64 + tid];
        lW2t[tid][14] = mb1[tid];
        lW2t[tid][15] = cb1[tid];
    }
    __syncthreads();

    const size_t r = (size_t)blockIdx.x * 256 + tid;  // 0..409599

    float o16[16];
    {
        const float4* op = (const float4*)(dec_o + r * 16);
        #pragma unroll
        for (int c = 0; c < 4; ++c) {
            float4 v = op[c];
            o16[4 * c + 0] = v.x; o16[4 * c + 1] = v.y;
            o16[4 * c + 2] = v.z; o16[4 * c + 3] = v.w;
        }
    }

    float m[4], cv[10];
    #pragma unroll
    for (int j = 0; j < 4; ++j)  m[j]  = mb2[j];
    #pragma unroll
    for (int j = 0; j < 10; ++j) cv[j] = cb2[j];

    #pragma unroll 4
    for (int hu = 0; hu < 64; ++hu) {
        const float4 a0 = *(const float4*)&lW1m[hu][0];
        const float4 a1 = *(const float4*)&lW1m[hu][4];
        const float4 a2 = *(const float4*)&lW1m[hu][8];
        const float4 a3 = *(const float4*)&lW1m[hu][12];
        const float4 c0 = *(const float4*)&lW1c[hu][0];
        const float4 c1 = *(const float4*)&lW1c[hu][4];
        const float4 c2 = *(const float4*)&lW1c[hu][8];
        const float4 c3 = *(const float4*)&lW1c[hu][12];
        const float4 t0 = *(const float4*)&lW2t[hu][0];
        const float4 t1 = *(const float4*)&lW2t[hu][4];
        const float4 t2 = *(const float4*)&lW2t[hu][8];
        const float4 t3 = *(const float4*)&lW2t[hu][12];

        float hm = t3.z;  // mb1[hu]
        hm = fmaf(a0.x, o16[0],  hm); hm = fmaf(a0.y, o16[1],  hm);
        hm = fmaf(a0.z, o16[2],  hm); hm = fmaf(a0.w, o16[3],  hm);
        hm = fmaf(a1.x, o16[4],  hm); hm = fmaf(a1.y, o16[5],  hm);
        hm = fmaf(a1.z, o16[6],  hm); hm = fmaf(a1.w, o16[7],  hm);
        hm = fmaf(a2.x, o16[8],  hm); hm = fmaf(a2.y, o16[9],  hm);
        hm = fmaf(a2.z, o16[10], hm); hm = fmaf(a2.w, o16[11], hm);
        hm = fmaf(a3.x, o16[12], hm); hm = fmaf(a3.y, o16[13], hm);
        hm = fmaf(a3.z, o16[14], hm); hm = fmaf(a3.w, o16[15], hm);
        float gm = gelu_fast(hm);
        m[0] = fmaf(t0.x, gm, m[0]); m[1] = fmaf(t0.y, gm, m[1]);
        m[2] = fmaf(t0.z, gm, m[2]); m[3] = fmaf(t0.w, gm, m[3]);

        float hc = t3.w;  // cb1[hu]
        hc = fmaf(c0.x, o16[0],  hc); hc = fmaf(c0.y, o16[1],  hc);
        hc = fmaf(c0.z, o16[2],  hc); hc = fmaf(c0.w, o16[3],  hc);
        hc = fmaf(c1.x, o16[4],  hc); hc = fmaf(c1.y, o16[5],  hc);
        hc = fmaf(c1.z, o16[6],  hc); hc = fmaf(c1.w, o16[7],  hc);
        hc = fmaf(c2.x, o16[8],  hc); hc = fmaf(c2.y, o16[9],  hc);
        hc = fmaf(c2.z, o16[10], hc); hc = fmaf(c2.w, o16[11], hc);
        hc = fmaf(c3.x, o16[12], hc); hc = fmaf(c3.y, o16[13], hc);
        hc = fmaf(c3.z, o16[14], hc); hc = fmaf(c3.w, o16[15], hc);
        float gc = gelu_fast(hc);
        cv[0] = fmaf(t1.x, gc, cv[0]); cv[1] = fmaf(t1.y, gc, cv[1]);
        cv[2] = fmaf(t1.z, gc, cv[2]); cv[3] = fmaf(t1.w, gc, cv[3]);
        cv[4] = fmaf(t2.x, gc, cv[4]); cv[5] = fmaf(t2.y, gc, cv[5]);
        cv[6] = fmaf(t2.z, gc, cv[6]); cv[7] = fmaf(t2.w, gc, cv[7]);
        cv[8] = fmaf(t3.x, gc, cv[8]); cv[9] = fmaf(t3.y, gc, cv[9]);
    }

    m[2] = fminf(fmaxf(m[2], -1.0f), 1.0f);
    m[3] = fminf(fmaxf(m[3], -1.0f), 1.0f);

    float* means = out;
    float* covs  = out + MEANS_N;
    #pragma unroll
    for (int j = 0; j < 4; ++j)  means[r * 4 + j]  = m[j];
    #pragma unroll
    for (int j = 0; j < 10; ++j) covs[r * 10 + j]  = cv[j];
}

// =====================================================================
extern "C" void kernel_launch(void* const* d_in, const int* in_sizes, int n_in,
                              void* d_out, int out_size, void* d_ws, size_t ws_size,
                              hipStream_t stream)
{
    const float* x    = (const float*)d_in[0];
    const float* trg  = (const float*)d_in[1];
    const float* eWih = (const float*)d_in[2];
    const float* ebih = (const float*)d_in[3];
    const float* eWhh = (const float*)d_in[4];
    const float* ebhh = (const float*)d_in[5];
    const float* dWih = (const float*)d_in[6];
    const float* dbih = (const float*)d_in[7];
    const float* dWhh = (const float*)d_in[8];
    const float* dbhh = (const float*)d_in[9];
    const float* outW = (const float*)d_in[10];
    const float* outb = (const float*)d_in[11];
    const float* embW = (const float*)d_in[12];
    const float* embb = (const float*)d_in[13];
    const float* mW1  = (const float*)d_in[14];
    const float* mb1  = (const float*)d_in[15];
    const float* mW2  = (const float*)d_in[16];
    const float* mb2  = (const float*)d_in[17];
    const float* cW1  = (const float*)d_in[18];
    const float* cb1  = (const float*)d_in[19];
    const float* cW2  = (const float*)d_in[20];
    const float* cb2  = (const float*)d_in[21];

    float* ws    = (float*)d_ws;
    float* enc_h = ws;                          // 4096*64      = 262144 floats
    float* dec_o = ws + (size_t)BTOT * HDIM;    // 4096*100*16  = 6553600 floats
    float* outp  = (float*)d_out;

    enc_mfma_kernel<<<dim3(BTOT / 8), dim3(256), 0, stream>>>(x, eWih, ebih, eWhh, ebhh, enc_h);
    dec_mfma_kernel<<<dim3(BTOT / 8), dim3(256), 0, stream>>>(trg, dWih, dbih, dWhh, dbhh,
                                                              outW, outb, embW, embb, enc_h, dec_o);
    heads_kernel<<<dim3((BTOT * SEQLEN) / 256), dim3(256), 0, stream>>>(
        dec_o, mW1, mb1, mW2, mb2, cW1, cb1, cW2, cb2, outp);
}